// Round 10
// baseline (48.495 us; speedup 1.0000x reference)
//
#include <hip/hip_runtime.h>

// out(p) = (49 - g·G)/8,  g = x/max(||x||_C,1e-8),
// G = 7x7 zero-padded box-sum of g (separable 7-tap H then V).
// Wave-autonomous 64x16 tiles (2 out rows per lane): fused load+normalize+
// H-pass in registers, wave-private bf16 h in LDS, center-g in registers,
// NO block barrier (each wave reads only its own hsh slice; wave-local
// s_waitcnt lgkmcnt(0) orders ds_write -> ds_read).

typedef unsigned int u32;
typedef float f32x4 __attribute__((ext_vector_type(4)));

#define EPS2 1e-16f   // 1/max(sqrt(n2),1e-8) == rsq(max(n2,1e-16))

constexpr int HRS = 23;   // 22 h rows (16 out + 6 halo) + 1 pad (odd stride)

__device__ __forceinline__ u32 packbf2(float a, float b) {
    // round-half-up bf16 pack (a=lo, b=hi); inputs finite & bounded
    const u32 ua = __float_as_uint(a), ub = __float_as_uint(b);
    return ((ua + 0x8000u) >> 16) | ((ub + 0x8000u) & 0xffff0000u);
}
__device__ __forceinline__ float uplo(u32 u) { return __uint_as_float(u << 16); }
__device__ __forceinline__ float uphi(u32 u) { return __uint_as_float(u & 0xffff0000u); }
__device__ __forceinline__ f32x4 vmul(f32x4 v, float s) {
    f32x4 r; r[0]=v[0]*s; r[1]=v[1]*s; r[2]=v[2]*s; r[3]=v[3]*s; return r;
}

__global__ __launch_bounds__(256, 4) void mcnd_kernel(const float* __restrict__ x,
                                                      float* __restrict__ out,
                                                      int B, int H, int W) {
    // wave-private h: [wave][ch][grp][hr], uint4 = 8 bf16 cols. 35,328 B.
    __shared__ uint4 hsh[4][3][8][HRS];

    const int HW = H * W;
    const int tilesX = W >> 6;                     // 8  (block tile 64x64)
    const int tilesPerImg = tilesX * (H >> 6);     // 64

    // bijective XCD swizzle (grid 2048 % 8 == 0)
    const int cpx  = gridDim.x >> 3;
    const int wgid = (blockIdx.x & 7) * cpx + (blockIdx.x >> 3);
    const int b    = wgid / tilesPerImg;
    const int t    = wgid % tilesPerImg;
    const int ty   = t / tilesX;
    const int tx   = t - ty * tilesX;
    const int x0   = tx << 6;

    const int wv   = threadIdx.x >> 6;             // wave id: 16-row strip
    const int lane = threadIdx.x & 63;
    const int r2   = lane >> 3;                    // 0..7 -> out rows 2r2, 2r2+1
    const int grp  = lane & 7;                     // 8-col group
    const int yw   = (ty << 6) + (wv << 4);        // wave's first out row

    const float* __restrict__ xb = x + (size_t)b * 3 * HW;

    // column geometry (cols gxl..gxl+15 cover out cols 8grp with +/-halo)
    const int   gxl   = x0 + (grp << 3) - 4;       // 16B-aligned
    const float lmask = (gxl >= 0) ? 1.f : 0.f;
    const float rmask = (gxl + 16 <= W) ? 1.f : 0.f;
    const int   gofL  = (gxl >= 0) ? gxl : 0;              // clamped, in-bounds
    const int   gofR  = (gxl + 16 <= W) ? (gxl + 12) : (W - 4);

    u32 gA0[4], gA1[4], gA2[4];                    // center g, out row 2r2
    u32 gB0[4], gB1[4], gB2[4];                    // center g, out row 2r2+1

    auto process = [&](int hr, u32* cp0, u32* cp1, u32* cp2) {
        const int   gy  = yw + hr - 3;
        const float rmk = (gy >= 0 && gy < H) ? 1.f : 0.f;
        const int   gyc = gy < 0 ? 0 : (gy >= H ? H - 1 : gy);
        const float* rp0 = xb + (size_t)gyc * W;
        const float* rp1 = rp0 + HW;
        const float* rp2 = rp1 + HW;
        // unconditional loads from clamped (always valid) addresses
        f32x4 a0 = *(const f32x4*)(rp0 + gofL);
        f32x4 a1 = *(const f32x4*)(rp0 + gxl + 4);
        f32x4 a2 = *(const f32x4*)(rp0 + gxl + 8);
        f32x4 a3 = *(const f32x4*)(rp0 + gofR);
        f32x4 b0 = *(const f32x4*)(rp1 + gofL);
        f32x4 b1 = *(const f32x4*)(rp1 + gxl + 4);
        f32x4 b2 = *(const f32x4*)(rp1 + gxl + 8);
        f32x4 b3 = *(const f32x4*)(rp1 + gofR);
        f32x4 c0 = *(const f32x4*)(rp2 + gofL);
        f32x4 c1 = *(const f32x4*)(rp2 + gxl + 4);
        f32x4 c2 = *(const f32x4*)(rp2 + gxl + 8);
        f32x4 c3 = *(const f32x4*)(rp2 + gofR);
        // zero out-of-image column chunks (finite values -> 0*v == 0)
        a0 = vmul(a0, lmask); b0 = vmul(b0, lmask); c0 = vmul(c0, lmask);
        a3 = vmul(a3, rmask); b3 = vmul(b3, rmask); c3 = vmul(c3, rmask);
        // per-column inverse norm (row mask folded in)
        f32x4 i0, i1, i2, i3;
        {
            const f32x4 n0 = a0*a0 + b0*b0 + c0*c0;
            const f32x4 n1 = a1*a1 + b1*b1 + c1*c1;
            const f32x4 n2 = a2*a2 + b2*b2 + c2*c2;
            const f32x4 n3 = a3*a3 + b3*b3 + c3*c3;
#pragma unroll
            for (int e = 0; e < 4; ++e) {
                i0[e] = __builtin_amdgcn_rsqf(fmaxf(n0[e], EPS2)) * rmk;
                i1[e] = __builtin_amdgcn_rsqf(fmaxf(n1[e], EPS2)) * rmk;
                i2[e] = __builtin_amdgcn_rsqf(fmaxf(n2[e], EPS2)) * rmk;
                i3[e] = __builtin_amdgcn_rsqf(fmaxf(n3[e], EPS2)) * rmk;
            }
        }
        auto chan = [&](const f32x4& A0, const f32x4& A1, const f32x4& A2,
                        const f32x4& A3, int ch, u32* gcp) {
            float cc[16];
#pragma unroll
            for (int e = 0; e < 4; ++e) {
                cc[e]      = A0[e] * i0[e];
                cc[4 + e]  = A1[e] * i1[e];
                cc[8 + e]  = A2[e] * i2[e];
                cc[12 + e] = A3[e] * i3[e];
            }
            // h for out col 8grp+m: staged cols m+1..m+7
            float hp[8];
            hp[0] = cc[1]+cc[2]+cc[3]+cc[4]+cc[5]+cc[6]+cc[7];
#pragma unroll
            for (int m = 1; m < 8; ++m) hp[m] = hp[m-1] - cc[m] + cc[m+7];
            uint4 hwv;
            hwv.x = packbf2(hp[0], hp[1]); hwv.y = packbf2(hp[2], hp[3]);
            hwv.z = packbf2(hp[4], hp[5]); hwv.w = packbf2(hp[6], hp[7]);
            hsh[wv][ch][grp][hr] = hwv;
            if (gcp) {                             // center g = local cols 4..11
                gcp[0] = packbf2(cc[4],  cc[5]);
                gcp[1] = packbf2(cc[6],  cc[7]);
                gcp[2] = packbf2(cc[8],  cc[9]);
                gcp[3] = packbf2(cc[10], cc[11]);
            }
        };
        chan(a0, a1, a2, a3, 0, cp0);
        chan(b0, b1, b2, b3, 1, cp1);
        chan(c0, c1, c2, c3, 2, cp2);
    };

    // iters 0/1: the lane's own two output rows (capture center g)
    process(2*r2 + 3, gA0, gA1, gA2);
    process(2*r2 + 4, gB0, gB1, gB2);
    // iter 2: halo rows {0,1,2,19,20,21} on lanes 0..47
    if (lane < 48) {
        const int rr = lane >> 3;                  // 0..5
        process(rr < 3 ? rr : rr + 16, nullptr, nullptr, nullptr);
    }
    // wave-local fence (this wave only reads hsh[wv], written by its own lanes)
    asm volatile("s_waitcnt lgkmcnt(0)" ::: "memory");
    __builtin_amdgcn_sched_barrier(0);

    // ---- vertical 7-tap (sliding over 2 rows) + dot + store ----
    float D0[8] = {0.f,0.f,0.f,0.f,0.f,0.f,0.f,0.f};
    float D1[8] = {0.f,0.f,0.f,0.f,0.f,0.f,0.f,0.f};
    auto vch = [&](int ch, const u32* ga, const u32* gb) {
        float acc[8] = {0.f,0.f,0.f,0.f,0.f,0.f,0.f,0.f};
        float f0[8], f7[8];
#pragma unroll
        for (int d = 0; d < 8; ++d) {
            const uint4 u = hsh[wv][ch][grp][2*r2 + d];
            float a[8];
            a[0] = uplo(u.x); a[1] = uphi(u.x);
            a[2] = uplo(u.y); a[3] = uphi(u.y);
            a[4] = uplo(u.z); a[5] = uphi(u.z);
            a[6] = uplo(u.w); a[7] = uphi(u.w);
            if (d == 0) {
#pragma unroll
                for (int e = 0; e < 8; ++e) f0[e] = a[e];
            }
            if (d == 7) {
#pragma unroll
                for (int e = 0; e < 8; ++e) f7[e] = a[e];
            } else {
#pragma unroll
                for (int e = 0; e < 8; ++e) acc[e] += a[e];
            }
        }
#pragma unroll
        for (int e = 0; e < 8; ++e) {
            const u32 gau = ga[e >> 1], gbu = gb[e >> 1];
            const float gav = (e & 1) ? uphi(gau) : uplo(gau);
            const float gbv = (e & 1) ? uphi(gbu) : uplo(gbu);
            D0[e] += gav * acc[e];
            D1[e] += gbv * (acc[e] - f0[e] + f7[e]);
        }
    };
    vch(0, gA0, gB0); vch(1, gA1, gB1); vch(2, gA2, gB2);

    f32x4 o00, o01, o10, o11;
#pragma unroll
    for (int e = 0; e < 8; ++e) {
        const float v0 = (49.0f - D0[e]) * 0.125f;
        const float v1 = (49.0f - D1[e]) * 0.125f;
        if (e < 4) { o00[e] = v0; o10[e] = v1; }
        else       { o01[e - 4] = v0; o11[e - 4] = v1; }
    }
    float* op = out + (size_t)b * HW + (size_t)(yw + 2*r2) * W + (x0 + (grp << 3));
    *(f32x4*)(op)         = o00;
    *(f32x4*)(op + 4)     = o01;
    *(f32x4*)(op + W)     = o10;
    *(f32x4*)(op + W + 4) = o11;
}

extern "C" void kernel_launch(void* const* d_in, const int* in_sizes, int n_in,
                              void* d_out, int out_size, void* d_ws, size_t ws_size,
                              hipStream_t stream) {
    (void)n_in; (void)d_ws; (void)ws_size; (void)out_size;
    const float* x = (const float*)d_in[0];
    float* out = (float*)d_out;

    const int H = 512, W = 512, C = 3;
    const int B = in_sizes[0] / (C * H * W);       // 32

    const int tilesPerImg = (W >> 6) * (H >> 6);   // 64
    mcnd_kernel<<<B * tilesPerImg, 256, 0, stream>>>(x, out, B, H, W);
}

// Round 11
// 35.320 us; speedup vs baseline: 1.3730x; 1.3730x over previous
//
#include <hip/hip_runtime.h>

// out(p) = (49 - g·G)/8,  g = x/max(||x||_C,1e-8),
// G = 7x7 zero-padded box-sum of g (separable 7-tap H then V).
// Wave-autonomous 64x8 tiles: fused load+normalize+H-pass in registers,
// wave-private bf16 h in LDS, center-g packed in registers, NO block barrier
// (each wave reads only its own hsh slice; wave-local s_waitcnt lgkmcnt(0)
// orders ds_write -> ds_read). LDS layout [hr][grp]: grp innermost => every
// wave b128 op hits 8 consecutive uint4 addrs per 8-lane group = all 32 banks
// exactly once (conflict-free by construction).

typedef unsigned int u32;
typedef float f32x2 __attribute__((ext_vector_type(2)));
typedef float f32x4 __attribute__((ext_vector_type(4)));

#define EPS2 1e-16f   // 1/max(sqrt(n2),1e-8) == rsq(max(n2,1e-16))

constexpr int HR = 14;   // h rows per wave tile (8 out rows + 6 halo)

__device__ __forceinline__ u32 packbf2(float a, float b) {
    // round-half-up bf16 pack (a=lo, b=hi) via v_perm_b32: 3 instructions
    const u32 ua = __float_as_uint(a) + 0x8000u;
    const u32 ub = __float_as_uint(b) + 0x8000u;
    return __builtin_amdgcn_perm(ub, ua, 0x07060302u);  // {ub.b3,ub.b2,ua.b3,ua.b2}
}
__device__ __forceinline__ float uplo(u32 u) { return __uint_as_float(u << 16); }
__device__ __forceinline__ float uphi(u32 u) { return __uint_as_float(u & 0xffff0000u); }
__device__ __forceinline__ f32x2 up2(u32 u) {
    f32x2 r; r.x = uplo(u); r.y = uphi(u); return r;
}
__device__ __forceinline__ f32x4 vmul(f32x4 v, float s) {
    f32x4 r; r[0]=v[0]*s; r[1]=v[1]*s; r[2]=v[2]*s; r[3]=v[3]*s; return r;
}

__global__ __launch_bounds__(256, 4) void mcnd_kernel(const float* __restrict__ x,
                                                      float* __restrict__ out,
                                                      int B, int H, int W) {
    // wave-private h: [wave][ch][hr][grp], uint4 = 8 bf16 cols. 21,504 B.
    __shared__ uint4 hsh[4][3][HR][8];

    const int HW = H * W;
    const int tilesX = W >> 6;                     // 8
    const int tilesPerImg = tilesX * (H >> 5);     // 128

    // bijective XCD swizzle (grid 4096 % 8 == 0)
    const int cpx  = gridDim.x >> 3;
    const int wgid = (blockIdx.x & 7) * cpx + (blockIdx.x >> 3);
    const int b    = wgid / tilesPerImg;
    const int t    = wgid % tilesPerImg;
    const int ty   = t / tilesX;
    const int tx   = t - ty * tilesX;
    const int x0   = tx << 6;

    const int wv   = threadIdx.x >> 6;             // wave id: 8-row strip
    const int lane = threadIdx.x & 63;
    const int r    = lane >> 3;                    // out row within strip
    const int grp  = lane & 7;                     // 8-col group
    const int yw   = (ty << 5) + (wv << 3);        // wave's first out row

    const float* __restrict__ xb = x + (size_t)b * 3 * HW;

    // column geometry for this lane (cols gxl..gxl+15 cover out cols 8grp±halo)
    const int   gxl   = x0 + (grp << 3) - 4;       // 16B-aligned
    const float lmask = (gxl >= 0) ? 1.f : 0.f;
    const float rmask = (gxl + 16 <= W) ? 1.f : 0.f;
    const int   gofL  = (gxl >= 0) ? gxl : 0;              // clamped, in-bounds
    const int   gofR  = (gxl + 16 <= W) ? (gxl + 12) : (W - 4);

    u32 gc0[4], gc1[4], gc2[4];                    // center g, packed bf16

    auto process = [&](int hr, bool capture) {
        const int   gy  = yw + hr - 3;
        const float rmk = (gy >= 0 && gy < H) ? 1.f : 0.f;
        const int   gyc = gy < 0 ? 0 : (gy >= H ? H - 1 : gy);
        const float* rp0 = xb + (size_t)gyc * W;
        const float* rp1 = rp0 + HW;
        const float* rp2 = rp1 + HW;
        // unconditional loads from clamped (always valid) addresses
        f32x4 a0 = *(const f32x4*)(rp0 + gofL);
        f32x4 a1 = *(const f32x4*)(rp0 + gxl + 4);
        f32x4 a2 = *(const f32x4*)(rp0 + gxl + 8);
        f32x4 a3 = *(const f32x4*)(rp0 + gofR);
        f32x4 b0 = *(const f32x4*)(rp1 + gofL);
        f32x4 b1 = *(const f32x4*)(rp1 + gxl + 4);
        f32x4 b2 = *(const f32x4*)(rp1 + gxl + 8);
        f32x4 b3 = *(const f32x4*)(rp1 + gofR);
        f32x4 c0 = *(const f32x4*)(rp2 + gofL);
        f32x4 c1 = *(const f32x4*)(rp2 + gxl + 4);
        f32x4 c2 = *(const f32x4*)(rp2 + gxl + 8);
        f32x4 c3 = *(const f32x4*)(rp2 + gofR);
        // zero the out-of-image column chunks (values finite -> 0*v == 0)
        a0 = vmul(a0, lmask); b0 = vmul(b0, lmask); c0 = vmul(c0, lmask);
        a3 = vmul(a3, rmask); b3 = vmul(b3, rmask); c3 = vmul(c3, rmask);
        // per-column inverse norm (row mask folded in)
        f32x4 i0, i1, i2, i3;
        {
            const f32x4 n0 = a0*a0 + b0*b0 + c0*c0;
            const f32x4 n1 = a1*a1 + b1*b1 + c1*c1;
            const f32x4 n2 = a2*a2 + b2*b2 + c2*c2;
            const f32x4 n3 = a3*a3 + b3*b3 + c3*c3;
#pragma unroll
            for (int e = 0; e < 4; ++e) {
                i0[e] = __builtin_amdgcn_rsqf(fmaxf(n0[e], EPS2)) * rmk;
                i1[e] = __builtin_amdgcn_rsqf(fmaxf(n1[e], EPS2)) * rmk;
                i2[e] = __builtin_amdgcn_rsqf(fmaxf(n2[e], EPS2)) * rmk;
                i3[e] = __builtin_amdgcn_rsqf(fmaxf(n3[e], EPS2)) * rmk;
            }
        }
        auto chan = [&](const f32x4& A0, const f32x4& A1, const f32x4& A2,
                        const f32x4& A3, int ch, u32* gcp) {
            float cc[16];
#pragma unroll
            for (int e = 0; e < 4; ++e) {
                cc[e]      = A0[e] * i0[e];
                cc[4 + e]  = A1[e] * i1[e];
                cc[8 + e]  = A2[e] * i2[e];
                cc[12 + e] = A3[e] * i3[e];
            }
            // h for out col 8grp+m: staged cols m+1..m+7
            float hp[8];
            hp[0] = cc[1]+cc[2]+cc[3]+cc[4]+cc[5]+cc[6]+cc[7];
#pragma unroll
            for (int m = 1; m < 8; ++m) hp[m] = hp[m-1] - cc[m] + cc[m+7];
            uint4 hwv;
            hwv.x = packbf2(hp[0], hp[1]); hwv.y = packbf2(hp[2], hp[3]);
            hwv.z = packbf2(hp[4], hp[5]); hwv.w = packbf2(hp[6], hp[7]);
            hsh[wv][ch][hr][grp] = hwv;
            if (capture) {                         // center g = local cols 4..11
                gcp[0] = packbf2(cc[4],  cc[5]);
                gcp[1] = packbf2(cc[6],  cc[7]);
                gcp[2] = packbf2(cc[8],  cc[9]);
                gcp[3] = packbf2(cc[10], cc[11]);
            }
        };
        chan(a0, a1, a2, a3, 0, gc0);
        chan(b0, b1, b2, b3, 1, gc1);
        chan(c0, c1, c2, c3, 2, gc2);
    };

    // iter0: hr = r+3 (the lane's own output row -> capture center g)
    process(r + 3, true);
    // iter1: remaining halo rows {0,1,2,11,12,13} on lanes 0..47
    if (lane < 48) {
        const int rr = lane >> 3;                  // 0..5
        process(rr < 3 ? rr : rr + 8, false);
    }
    // wave-local fence instead of __syncthreads: this wave only reads hsh[wv],
    // written by its own (lockstep) lanes. Order ds_writes before ds_reads.
    asm volatile("s_waitcnt lgkmcnt(0)" ::: "memory");
    __builtin_amdgcn_sched_barrier(0);

    // ---- vertical 7-tap + dot + store (f32x2 ops -> v_pk_add/fma_f32) ----
    f32x2 D[4];
#pragma unroll
    for (int e = 0; e < 4; ++e) D[e] = f32x2{0.f, 0.f};
    auto vch = [&](int ch, const u32* gcp) {
        f32x2 s[4];
#pragma unroll
        for (int e = 0; e < 4; ++e) s[e] = f32x2{0.f, 0.f};
#pragma unroll
        for (int d = 0; d < 7; ++d) {
            const uint4 u = hsh[wv][ch][r + d][grp];
            s[0] += up2(u.x);
            s[1] += up2(u.y);
            s[2] += up2(u.z);
            s[3] += up2(u.w);
        }
#pragma unroll
        for (int e = 0; e < 4; ++e) {
            D[e] += up2(gcp[e]) * s[e];
        }
    };
    vch(0, gc0); vch(1, gc1); vch(2, gc2);

    f32x4 o0, o1;
#pragma unroll
    for (int e = 0; e < 4; ++e) {
        const f32x2 v = (f32x2{49.f, 49.f} - D[e]) * 0.125f;
        if (e < 2) { o0[2*e] = v.x; o0[2*e + 1] = v.y; }
        else       { o1[2*(e-2)] = v.x; o1[2*(e-2) + 1] = v.y; }
    }
    float* op = out + (size_t)b * HW + (size_t)(yw + r) * W + (x0 + (grp << 3));
    *(f32x4*)(op)     = o0;                        // 8 lanes = 256B span
    *(f32x4*)(op + 4) = o1;
}

extern "C" void kernel_launch(void* const* d_in, const int* in_sizes, int n_in,
                              void* d_out, int out_size, void* d_ws, size_t ws_size,
                              hipStream_t stream) {
    (void)n_in; (void)d_ws; (void)ws_size; (void)out_size;
    const float* x = (const float*)d_in[0];
    float* out = (float*)d_out;

    const int H = 512, W = 512, C = 3;
    const int B = in_sizes[0] / (C * H * W);       // 32

    const int tilesPerImg = (W >> 6) * (H >> 5);   // 128
    mcnd_kernel<<<B * tilesPerImg, 256, 0, stream>>>(x, out, B, H, W);
}